// Round 1
// baseline (589.903 us; speedup 1.0000x reference)
//
#include <hip/hip_runtime.h>

// Problem constants (fixed instance): x [B,S,F], Wq/Wk/Wv [F,D], out [B,S,D]
constexpr int Bc = 4, Sc = 4096, Fc = 512, Dc = 64;

// ---------------------------------------------------------------------------
// Stage 1: QKV projection. grid = (B*S/64, 3), block = 256.
// Tiled fp32 GEMM: 64 rows x 64 cols per block, K-chunks of 32.
// Scale 1/sqrt(D)=0.125 folded into Q so attention is just Q'.K^T.
// ---------------------------------------------------------------------------
__global__ __launch_bounds__(256) void qkv_kernel(
    const float* __restrict__ x, const float* __restrict__ Wq,
    const float* __restrict__ Wk, const float* __restrict__ Wv,
    float* __restrict__ Q, float* __restrict__ K, float* __restrict__ V)
{
    __shared__ float As[64][33];   // x tile [row][k], pad 33 to break conflicts
    __shared__ float Bs[32][64];   // W tile [k][d] (k fixed during reads -> no pad needed)
    const int t = threadIdx.x;
    const int which = blockIdx.y;
    const float* __restrict__ W = (which == 0) ? Wq : (which == 1) ? Wk : Wv;
    float* __restrict__ Out = (which == 0) ? Q : (which == 1) ? K : V;
    const float scale = (which == 0) ? 0.125f : 1.0f;
    const int row0 = blockIdx.x * 64;
    const int r0 = (t >> 4) * 4;   // 4 rows per thread
    const int c0 = (t & 15) * 4;   // 4 cols per thread

    float acc[4][4] = {};
    for (int f0 = 0; f0 < Fc; f0 += 32) {
        #pragma unroll
        for (int i = 0; i < 8; ++i) {          // 64x32 x-tile, coalesced
            int e = t + i * 256;
            int r = e >> 5, k = e & 31;
            As[r][k] = x[(size_t)(row0 + r) * Fc + f0 + k];
        }
        #pragma unroll
        for (int i = 0; i < 8; ++i) {          // 32x64 W-tile, coalesced
            int e = t + i * 256;
            int k = e >> 6, d = e & 63;
            Bs[k][d] = W[(size_t)(f0 + k) * Dc + d];
        }
        __syncthreads();
        #pragma unroll
        for (int kk = 0; kk < 32; ++kk) {
            float a[4], bb[4];
            #pragma unroll
            for (int i = 0; i < 4; ++i) a[i] = As[r0 + i][kk];
            #pragma unroll
            for (int j = 0; j < 4; ++j) bb[j] = Bs[kk][c0 + j];
            #pragma unroll
            for (int i = 0; i < 4; ++i)
                #pragma unroll
                for (int j = 0; j < 4; ++j)
                    acc[i][j] += a[i] * bb[j];
        }
        __syncthreads();
    }
    #pragma unroll
    for (int i = 0; i < 4; ++i) {
        float4 vv = make_float4(acc[i][0] * scale, acc[i][1] * scale,
                                acc[i][2] * scale, acc[i][3] * scale);
        *(float4*)&Out[(size_t)(row0 + r0 + i) * Dc + c0] = vv;
    }
}

// ---------------------------------------------------------------------------
// Stage 2: flash-style attention, fp32 vector. grid = (S/64, B), block = 256.
// Per block: 64 q-rows; iterate 64-key tiles with online softmax.
// Thread (tr,tc) owns 4 rows x 4 cols in both score and PV phases.
// LDS pads of 65 -> worst-case 2-way bank conflicts (free on wave64).
// ---------------------------------------------------------------------------
__global__ __launch_bounds__(256) void attn_kernel(
    const float* __restrict__ Q, const float* __restrict__ K,
    const float* __restrict__ V, float* __restrict__ Out)
{
    __shared__ float Qt[64][65];
    __shared__ float Kt[64][65];
    __shared__ float Vt[64][65];
    __shared__ float Ps[64][65];
    const int t = threadIdx.x;
    const int b = blockIdx.y;
    const int q0 = blockIdx.x * 64;
    const size_t base = (size_t)b * Sc * Dc;
    const int tr = t >> 4, tc = t & 15;
    const int r0 = tr * 4, c0 = tc * 4;

    #pragma unroll
    for (int i = 0; i < 16; ++i) {             // load Q tile (already 0.125-scaled)
        int e = t + i * 256;
        int r = e >> 6, d = e & 63;
        Qt[r][d] = Q[base + (size_t)(q0 + r) * Dc + d];
    }

    float m_i[4], l_i[4], O[4][4];
    #pragma unroll
    for (int i = 0; i < 4; ++i) {
        m_i[i] = -1e30f; l_i[i] = 0.f;
        #pragma unroll
        for (int j = 0; j < 4; ++j) O[i][j] = 0.f;
    }

    for (int kt = 0; kt < Sc / 64; ++kt) {
        const int k0 = kt * 64;
        __syncthreads();                        // protect Kt/Vt/Ps from prev iter
        #pragma unroll
        for (int i = 0; i < 16; ++i) {
            int e = t + i * 256;
            int r = e >> 6, d = e & 63;
            Kt[r][d] = K[base + (size_t)(k0 + r) * Dc + d];
            Vt[r][d] = V[base + (size_t)(k0 + r) * Dc + d];
        }
        __syncthreads();

        // --- scores: s[i][j] = Q'[r0+i] . K[c0+j] over d=64 ---
        float s[4][4] = {};
        #pragma unroll 8
        for (int d = 0; d < 64; ++d) {
            float a[4], bb[4];
            #pragma unroll
            for (int i = 0; i < 4; ++i) a[i] = Qt[r0 + i][d];
            #pragma unroll
            for (int j = 0; j < 4; ++j) bb[j] = Kt[c0 + j][d];
            #pragma unroll
            for (int i = 0; i < 4; ++i)
                #pragma unroll
                for (int j = 0; j < 4; ++j)
                    s[i][j] += a[i] * bb[j];
        }

        // --- online softmax (row groups = 16 lanes sharing same tr, intra-wave) ---
        float mt[4];
        #pragma unroll
        for (int i = 0; i < 4; ++i) {
            mt[i] = fmaxf(fmaxf(s[i][0], s[i][1]), fmaxf(s[i][2], s[i][3]));
        }
        #pragma unroll
        for (int off = 8; off >= 1; off >>= 1)
            #pragma unroll
            for (int i = 0; i < 4; ++i)
                mt[i] = fmaxf(mt[i], __shfl_xor(mt[i], off, 16));

        float alpha[4], rs[4];
        #pragma unroll
        for (int i = 0; i < 4; ++i) {
            float mn = fmaxf(m_i[i], mt[i]);
            alpha[i] = __expf(m_i[i] - mn);
            m_i[i] = mn;
            float r = 0.f;
            #pragma unroll
            for (int j = 0; j < 4; ++j) {
                float p = __expf(s[i][j] - mn);
                s[i][j] = p;
                r += p;
            }
            rs[i] = r;
        }
        #pragma unroll
        for (int off = 8; off >= 1; off >>= 1)
            #pragma unroll
            for (int i = 0; i < 4; ++i)
                rs[i] += __shfl_xor(rs[i], off, 16);
        #pragma unroll
        for (int i = 0; i < 4; ++i)
            l_i[i] = l_i[i] * alpha[i] + rs[i];

        #pragma unroll
        for (int i = 0; i < 4; ++i)
            #pragma unroll
            for (int j = 0; j < 4; ++j) {
                Ps[r0 + i][c0 + j] = s[i][j];
                O[i][j] *= alpha[i];
            }
        __syncthreads();                        // Ps + (Vt still valid)

        // --- PV: O[i][jd] += sum_key Ps[row][key] * Vt[key][col] ---
        #pragma unroll 8
        for (int key = 0; key < 64; ++key) {
            float pr[4], vv[4];
            #pragma unroll
            for (int i = 0; i < 4; ++i) pr[i] = Ps[r0 + i][key];
            #pragma unroll
            for (int j = 0; j < 4; ++j) vv[j] = Vt[key][c0 + j];
            #pragma unroll
            for (int i = 0; i < 4; ++i)
                #pragma unroll
                for (int j = 0; j < 4; ++j)
                    O[i][j] += pr[i] * vv[j];
        }
    }

    #pragma unroll
    for (int i = 0; i < 4; ++i) {
        float inv = 1.f / l_i[i];
        float4 vv = make_float4(O[i][0] * inv, O[i][1] * inv,
                                O[i][2] * inv, O[i][3] * inv);
        *(float4*)&Out[base + (size_t)(q0 + r0 + i) * Dc + c0] = vv;
    }
}

// ---------------------------------------------------------------------------
extern "C" void kernel_launch(void* const* d_in, const int* in_sizes, int n_in,
                              void* d_out, int out_size, void* d_ws, size_t ws_size,
                              hipStream_t stream) {
    const float* x  = (const float*)d_in[0];
    const float* Wq = (const float*)d_in[1];
    const float* Wk = (const float*)d_in[2];
    const float* Wv = (const float*)d_in[3];
    float* out = (float*)d_out;

    // workspace: Q, K, V fp32 [B*S, D] each (4.19 MB each, 12.6 MB total)
    float* Q = (float*)d_ws;
    float* K = Q + (size_t)Bc * Sc * Dc;
    float* V = K + (size_t)Bc * Sc * Dc;

    qkv_kernel<<<dim3(Bc * Sc / 64, 3), 256, 0, stream>>>(x, Wq, Wk, Wv, Q, K, V);
    attn_kernel<<<dim3(Sc / 64, Bc), 256, 0, stream>>>(Q, K, V, out);
}

// Round 2
// 218.680 us; speedup vs baseline: 2.6976x; 2.6976x over previous
//
#include <hip/hip_runtime.h>

// Problem constants: x [B,S,F], Wq/Wk/Wv [F,D], out [B,S,D]
constexpr int Bc = 4, Sc = 4096, Fc = 512, Dc = 64;

typedef __attribute__((ext_vector_type(8))) short short8;   // 8 bf16 = 4 VGPRs
typedef __attribute__((ext_vector_type(4))) float float4v;  // MFMA C/D

__device__ inline unsigned short f2bf(float f) {
    union { float f; unsigned u; } v; v.f = f;
    unsigned r = v.u + 0x7FFF + ((v.u >> 16) & 1);  // RTNE
    return (unsigned short)(r >> 16);
}

// ---------------------------------------------------------------------------
// Stage 1: QKV projection, fp32 compute, bf16 outputs.
//   which==0 -> Qb  [B*S][64] bf16, scale 0.125 folded
//   which==1 -> Kb  [B*S][64] bf16
//   which==2 -> Vtb [B][64][S] bf16 (transposed via LDS bounce)
// ---------------------------------------------------------------------------
__global__ __launch_bounds__(256) void qkv_kernel(
    const float* __restrict__ x, const float* __restrict__ Wq,
    const float* __restrict__ Wk, const float* __restrict__ Wv,
    unsigned short* __restrict__ Qb, unsigned short* __restrict__ Kb,
    unsigned short* __restrict__ Vtb)
{
    __shared__ float As[64][33];
    __shared__ float Bs[32][64];
    __shared__ unsigned short Tt[64][72];   // V^T bounce tile
    const int t = threadIdx.x;
    const int which = blockIdx.y;
    const float* __restrict__ W = (which == 0) ? Wq : (which == 1) ? Wk : Wv;
    const int row0 = blockIdx.x * 64;
    const int r0 = (t >> 4) * 4;
    const int c0 = (t & 15) * 4;

    float acc[4][4] = {};
    for (int f0 = 0; f0 < Fc; f0 += 32) {
        #pragma unroll
        for (int i = 0; i < 8; ++i) {
            int e = t + i * 256;
            int r = e >> 5, k = e & 31;
            As[r][k] = x[(size_t)(row0 + r) * Fc + f0 + k];
        }
        #pragma unroll
        for (int i = 0; i < 8; ++i) {
            int e = t + i * 256;
            int k = e >> 6, d = e & 63;
            Bs[k][d] = W[(size_t)(f0 + k) * Dc + d];
        }
        __syncthreads();
        #pragma unroll
        for (int kk = 0; kk < 32; ++kk) {
            float a[4], bb[4];
            #pragma unroll
            for (int i = 0; i < 4; ++i) a[i] = As[r0 + i][kk];
            #pragma unroll
            for (int j = 0; j < 4; ++j) bb[j] = Bs[kk][c0 + j];
            #pragma unroll
            for (int i = 0; i < 4; ++i)
                #pragma unroll
                for (int j = 0; j < 4; ++j)
                    acc[i][j] += a[i] * bb[j];
        }
        __syncthreads();
    }

    if (which < 2) {
        unsigned short* __restrict__ Out = (which == 0) ? Qb : Kb;
        const float scale = (which == 0) ? 0.125f : 1.0f;
        #pragma unroll
        for (int i = 0; i < 4; ++i) {
            ushort4 vv;
            vv.x = f2bf(acc[i][0] * scale);
            vv.y = f2bf(acc[i][1] * scale);
            vv.z = f2bf(acc[i][2] * scale);
            vv.w = f2bf(acc[i][3] * scale);
            *(ushort4*)&Out[(size_t)(row0 + r0 + i) * Dc + c0] = vv;
        }
    } else {
        #pragma unroll
        for (int i = 0; i < 4; ++i)
            #pragma unroll
            for (int j = 0; j < 4; ++j)
                Tt[c0 + j][r0 + i] = f2bf(acc[i][j]);
        __syncthreads();
        const int b = row0 / Sc;
        const int s_off = row0 % Sc;
        const int d = t >> 2;
        const int cs = (t & 3) * 16;
        uint4* dst = (uint4*)&Vtb[(size_t)b * Dc * Sc + (size_t)d * Sc + s_off + cs];
        dst[0] = *(uint4*)&Tt[d][cs];
        dst[1] = *(uint4*)&Tt[d][cs + 8];
    }
}

// ---------------------------------------------------------------------------
// Stage 2: flash attention on MFMA. block = 256 (4 waves), 64 q-rows/block.
// Wave w owns q-rows q0+w*16 .. +15. Per 64-key tile:
//   QK^T: A=Q frags (regs, loaded once), B=K frags from LDS Kt[key][d]
//   online softmax in VALU (C layout: row=quad*4+reg, col=lane&15)
//   P -> wave-private LDS (A layout round trip), V from LDS Vt[d][key]
// LDS rows padded to 72 bf16 (9 bank-quads, odd stride -> conflict-free b128).
// ---------------------------------------------------------------------------
__global__ __launch_bounds__(256) void attn_kernel(
    const unsigned short* __restrict__ Qb, const unsigned short* __restrict__ Kb,
    const unsigned short* __restrict__ Vtb, float* __restrict__ Out)
{
    constexpr int PD = 72;
    __shared__ unsigned short Kt[64 * PD];      // [key][d]
    __shared__ unsigned short Vt[64 * PD];      // [d][key]
    __shared__ unsigned short Ps[4][16 * PD];   // wave-private [qrow][key]

    const int t = threadIdx.x;
    const int lane = t & 63, w = t >> 6;
    const int quad = lane >> 4, lm = lane & 15;
    const int b = blockIdx.y, q0 = blockIdx.x * 64;
    const size_t qkbase = (size_t)b * Sc * Dc;
    const size_t vbase = (size_t)b * Dc * Sc;

    // Q fragments: A[m=lm][k=quad*8+j], two K-halves of D=64
    short8 aQ0, aQ1;
    {
        const unsigned short* qrow = Qb + qkbase + (size_t)(q0 + w * 16 + lm) * Dc;
        aQ0 = *(const short8*)(qrow + quad * 8);
        aQ1 = *(const short8*)(qrow + 32 + quad * 8);
    }

    float m_i[4], l_i[4];
    float4v Oa[4];
    #pragma unroll
    for (int r = 0; r < 4; ++r) { m_i[r] = -1e30f; l_i[r] = 0.f; }
    #pragma unroll
    for (int n = 0; n < 4; ++n) Oa[n] = float4v{0.f, 0.f, 0.f, 0.f};

    // staging: 256 threads x 2 rows x 16B cover one 64x64 bf16 tile
    const int srow = t >> 3;
    const int schunk = (t & 7) * 8;

    uint4 kr0, kr1, vr0, vr1;
    auto load_tile = [&](int k0) {
        kr0 = *(const uint4*)(Kb + qkbase + (size_t)(k0 + srow) * Dc + schunk);
        kr1 = *(const uint4*)(Kb + qkbase + (size_t)(k0 + srow + 32) * Dc + schunk);
        vr0 = *(const uint4*)(Vtb + vbase + (size_t)srow * Sc + k0 + schunk);
        vr1 = *(const uint4*)(Vtb + vbase + (size_t)(srow + 32) * Sc + k0 + schunk);
    };
    load_tile(0);

    for (int kt = 0; kt < Sc / 64; ++kt) {
        __syncthreads();                       // previous tile's reads done
        *(uint4*)&Kt[srow * PD + schunk] = kr0;
        *(uint4*)&Kt[(srow + 32) * PD + schunk] = kr1;
        *(uint4*)&Vt[srow * PD + schunk] = vr0;
        *(uint4*)&Vt[(srow + 32) * PD + schunk] = vr1;
        __syncthreads();
        if (kt + 1 < Sc / 64) load_tile((kt + 1) * 64);  // prefetch overlaps compute

        // ---- QK^T: 4 key-subtiles of 16 ----
        float4v s4[4];
        #pragma unroll
        for (int s = 0; s < 4; ++s) {
            short8 b0 = *(const short8*)&Kt[(s * 16 + lm) * PD + quad * 8];
            short8 b1 = *(const short8*)&Kt[(s * 16 + lm) * PD + 32 + quad * 8];
            float4v z = {0.f, 0.f, 0.f, 0.f};
            z = __builtin_amdgcn_mfma_f32_16x16x32_bf16(aQ0, b0, z, 0, 0, 0);
            z = __builtin_amdgcn_mfma_f32_16x16x32_bf16(aQ1, b1, z, 0, 0, 0);
            s4[s] = z;
        }

        // ---- online softmax: lane holds rows quad*4+r, col lm (+16s) ----
        float alpha[4];
        #pragma unroll
        for (int r = 0; r < 4; ++r) {
            float mt = fmaxf(fmaxf(s4[0][r], s4[1][r]), fmaxf(s4[2][r], s4[3][r]));
            #pragma unroll
            for (int off = 8; off >= 1; off >>= 1)
                mt = fmaxf(mt, __shfl_xor(mt, off, 16));
            float mn = fmaxf(m_i[r], mt);
            alpha[r] = __expf(m_i[r] - mn);
            m_i[r] = mn;
            float rs = 0.f;
            #pragma unroll
            for (int s = 0; s < 4; ++s) {
                float p = __expf(s4[s][r] - mn);
                s4[s][r] = p;
                rs += p;
            }
            #pragma unroll
            for (int off = 8; off >= 1; off >>= 1)
                rs += __shfl_xor(rs, off, 16);
            l_i[r] = l_i[r] * alpha[r] + rs;
        }

        // ---- P -> LDS (wave-private; C layout out, A layout back in) ----
        #pragma unroll
        for (int s = 0; s < 4; ++s)
            #pragma unroll
            for (int r = 0; r < 4; ++r)
                Ps[w][(quad * 4 + r) * PD + s * 16 + lm] = f2bf(s4[s][r]);

        short8 aP0 = *(const short8*)&Ps[w][lm * PD + quad * 8];
        short8 aP1 = *(const short8*)&Ps[w][lm * PD + 32 + quad * 8];

        // ---- PV: 4 d-subtiles of 16 ----
        #pragma unroll
        for (int n = 0; n < 4; ++n) {
            short8 b0 = *(const short8*)&Vt[(n * 16 + lm) * PD + quad * 8];
            short8 b1 = *(const short8*)&Vt[(n * 16 + lm) * PD + 32 + quad * 8];
            float4v o = Oa[n];
            #pragma unroll
            for (int r = 0; r < 4; ++r) o[r] *= alpha[r];
            o = __builtin_amdgcn_mfma_f32_16x16x32_bf16(aP0, b0, o, 0, 0, 0);
            o = __builtin_amdgcn_mfma_f32_16x16x32_bf16(aP1, b1, o, 0, 0, 0);
            Oa[n] = o;
        }
    }

    // epilogue: normalize and store fp32
    #pragma unroll
    for (int r = 0; r < 4; ++r) {
        float inv = 1.f / l_i[r];
        int q = q0 + w * 16 + quad * 4 + r;
        #pragma unroll
        for (int n = 0; n < 4; ++n)
            Out[((size_t)b * Sc + q) * Dc + n * 16 + lm] = Oa[n][r] * inv;
    }
}

// ---------------------------------------------------------------------------
extern "C" void kernel_launch(void* const* d_in, const int* in_sizes, int n_in,
                              void* d_out, int out_size, void* d_ws, size_t ws_size,
                              hipStream_t stream) {
    const float* x  = (const float*)d_in[0];
    const float* Wq = (const float*)d_in[1];
    const float* Wk = (const float*)d_in[2];
    const float* Wv = (const float*)d_in[3];
    float* out = (float*)d_out;

    // workspace: Qb, Kb, Vtb bf16, 2 MB each (6 MB total)
    unsigned short* Qb  = (unsigned short*)d_ws;
    unsigned short* Kb  = Qb + (size_t)Bc * Sc * Dc;
    unsigned short* Vtb = Kb + (size_t)Bc * Sc * Dc;

    qkv_kernel<<<dim3(Bc * Sc / 64, 3), 256, 0, stream>>>(x, Wq, Wk, Wv, Qb, Kb, Vtb);
    attn_kernel<<<dim3(Sc / 64, Bc), 256, 0, stream>>>(Qb, Kb, Vtb, out);
}